// Round 25
// baseline (65.949 us; speedup 1.0000x reference)
//
#include <hip/hip_runtime.h>
#include <hip/hip_bf16.h>

#define DDIM   256    // K (feature dim)
#define BROWS  256    // block output rows (4 waves x 64 rows)
#define BN      64    // cols per N-tile
#define NT       8    // N-tiles per block -> 512-col chunk
#define TS   (BN * DDIM)   // 16 KB per buffer
#define NROWS  8192
#define NBLK   ((NROWS / BROWS) * (NROWS / (NT * BN)))   // 32 x 16 = 512
#define SQRT_LOG2E 1.2011224087864498f   // sqrt(log2(e)); dot *= log2(e)

typedef float f32x4 __attribute__((ext_vector_type(4)));
typedef int   i32x4 __attribute__((ext_vector_type(4)));
typedef int   i32x8 __attribute__((ext_vector_type(8)));

// v_exp_f32: D = 2^S0 (hardware transcendental)
__device__ __forceinline__ float exp2_hw(float x) {
  return __builtin_amdgcn_exp2f(x);
}

// MX-scaled fp8 MFMA, unit scales (E8M0 127 = 1.0). cbsz=0/blgp=0 -> e4m3.
__device__ __forceinline__ f32x4 mfma_mx(i32x8 a, i32x8 b, f32x4 c) {
  return __builtin_amdgcn_mfma_scale_f32_16x16x128_f8f6f4(
      a, b, c, 0, 0, 0, 0x7F7F7F7F, 0, 0x7F7F7F7F);
}

__device__ __forceinline__ i32x8 cat8(i32x4 lo, i32x4 hi) {
  return __builtin_shufflevector(lo, hi, 0, 1, 2, 3, 4, 5, 6, 7);
}

// pack 4 f32 -> 4 fp8 e4m3 bytes
__device__ __forceinline__ unsigned int pack4_fp8(float a0, float a1, float a2, float a3) {
  int v = __builtin_amdgcn_cvt_pk_fp8_f32(a0, a1, 0, false);   // bytes 0,1
  v = __builtin_amdgcn_cvt_pk_fp8_f32(a2, a3, v, true);        // bytes 2,3
  return (unsigned int)v;
}

// ---- prep: one wave per row; writes sqrt(log2e)-scaled UNIT-NORM fp8 rows
// (so the GEMM dot is s*log2e and the epilogue is a bare exp2) + exact diag.
__global__ __launch_bounds__(256) void prep_kernel(
    const float* __restrict__ q, const float* __restrict__ r,
    unsigned char* __restrict__ qf8, unsigned char* __restrict__ rf8,
    float* __restrict__ pos, float* __restrict__ row_sum,
    int* __restrict__ done_cnt) {
  if (blockIdx.x == 0 && threadIdx.x == 0) done_cnt[0] = 0;
  int lane = threadIdx.x & 63, wave = threadIdx.x >> 6;
  int row = blockIdx.x * 4 + wave;
  size_t base = (size_t)row * DDIM + lane * 4;
  float4 qv = *(const float4*)(q + base);
  float4 rv = *(const float4*)(r + base);
  float qq = qv.x*qv.x + qv.y*qv.y + qv.z*qv.z + qv.w*qv.w;
  float rr = rv.x*rv.x + rv.y*rv.y + rv.z*rv.z + rv.w*rv.w;
  float qr = qv.x*rv.x + qv.y*rv.y + qv.z*rv.z + qv.w*rv.w;
  #pragma unroll
  for (int m = 1; m < 64; m <<= 1) {
    qq += __shfl_xor(qq, m);
    rr += __shfl_xor(rr, m);
    qr += __shfl_xor(qr, m);
  }
  float iq0 = 1.0f / sqrtf(qq);
  float ir0 = 1.0f / sqrtf(rr);
  float iq = iq0 * SQRT_LOG2E;
  float ir = ir0 * SQRT_LOG2E;
  unsigned int qp = pack4_fp8(qv.x*iq, qv.y*iq, qv.z*iq, qv.w*iq);
  unsigned int rp = pack4_fp8(rv.x*ir, rv.y*ir, rv.z*ir, rv.w*ir);
  *(unsigned int*)(qf8 + base) = qp;
  *(unsigned int*)(rf8 + base) = rp;
  if (lane == 0) {
    pos[row] = qr * iq0 * ir0;   // exact f32 diagonal from raw inputs
    row_sum[row] = 0.0f;
  }
}

// stage quarter q of a 64-col fp8 tile: 1 load/thread into the LANE-LINEAR
// layout (R17-validated): chunk (col=p*32+cf*16+c, k16=h*8+g*2+pc) at index
// (p*8+cf*4+h*2+pc)*64 + (g*16+c) -> all ds_reads are base+lane*16+imm,
// zero bank conflicts. SOURCE applies the inverse permutation (rule 21).
__device__ __forceinline__ void stage_quarter(char* dstBase,
                                              const unsigned char* src_base,
                                              int col0, int q, int tid) {
  int ch = q * 256 + tid;              // dest chunk id 0..1023
  int c   = ch & 15;
  int g   = (ch >> 4) & 3;
  int pc  = (ch >> 6) & 1;
  int h   = (ch >> 7) & 1;
  int cf  = (ch >> 8) & 1;
  int p   = (ch >> 9) & 1;
  int col = p * 32 + cf * 16 + c;
  int src = col * 256 + h * 128 + g * 32 + pc * 16;
  __builtin_amdgcn_global_load_lds(
      (const __attribute__((address_space(1))) void*)((const char*)src_base + (size_t)col0 * 256 + src),
      (__attribute__((address_space(3))) void*)(dstBase + ch * 16),
      16, 0, 0);
}

// exp2-accumulate one phase's 32 scores into the per-row partials.
__device__ __forceinline__ void flush_acc(const f32x4 (&acc)[4][2], float (&rs)[16]) {
  #pragma unroll
  for (int m = 0; m < 4; ++m)
    #pragma unroll
    for (int jj = 0; jj < 4; ++jj)
      rs[m * 4 + jj] += exp2_hw(acc[m][0][jj]) + exp2_hw(acc[m][1][jj]);
}

// MX-K128 GEMM+LSE (R19 body, verbatim: best validated at 33.7 us) with the
// finalize FUSED as a last-block reduction — removes one kernel launch+gap.
__global__ __launch_bounds__(256, 2) void gemm_lse_kernel(
    const unsigned char* __restrict__ qf8, const unsigned char* __restrict__ rf8,
    float* __restrict__ row_sum, const float* __restrict__ pos,
    float* __restrict__ out, int* __restrict__ done_cnt) {
  __shared__ __attribute__((aligned(16))) unsigned char Bl[3 * TS];  // 48 KB

  const int tid  = threadIdx.x;
  const int lane = tid & 63;
  const int wid  = tid >> 6;            // 4 waves, each owns 64 rows
  const int g = lane >> 4, c = lane & 15;
  const int row0  = blockIdx.x * BROWS;
  const int col00 = blockIdx.y * (NT * BN);
  const unsigned char* Rb = rf8;

  // A fragments FIRST (oldest in vmcnt order), then stage tiles 0 and 1 —
  // the pre-loop vmcnt(4) completes av+tile0 and keeps tile1 in flight.
  i32x8 av[4][2];
  const char* Ab = (const char*)qf8;
  #pragma unroll
  for (int m = 0; m < 4; ++m) {
    size_t rb0 = (size_t)(row0 + wid * 64 + m * 16 + c) * 256;
    #pragma unroll
    for (int h = 0; h < 2; ++h) {
      const char* p = Ab + rb0 + h * 128 + g * 32;
      av[m][h] = cat8(*(const i32x4*)(p), *(const i32x4*)(p + 16));
    }
  }
  #pragma unroll
  for (int q = 0; q < 4; ++q) stage_quarter((char*)Bl,      Rb, col00,      q, tid);
  #pragma unroll
  for (int q = 0; q < 4; ++q) stage_quarter((char*)Bl + TS, Rb, col00 + BN, q, tid);

  float rs[16];
  #pragma unroll
  for (int k = 0; k < 16; ++k) rs[k] = 0.0f;

  // tile 0 resident; tile 1's 4 loads stay in flight
  asm volatile("s_waitcnt vmcnt(4)" ::: "memory");
  __builtin_amdgcn_s_barrier();

  const f32x4 zero = {0.f, 0.f, 0.f, 0.f};
  const f32x4 neg  = {-1000.f, -1000.f, -1000.f, -1000.f};  // exp2 -> 0
  f32x4 accA[4][2], accB[4][2];
  #pragma unroll
  for (int m = 0; m < 4; ++m) { accB[m][0] = neg; accB[m][1] = neg; }

  int rb = 0;            // read-buffer byte base (t % 3)
  int wb = 2 * TS;       // write-buffer byte base ((t+2) % 3)
  #pragma unroll 1       // R18 lesson: unrolling blows the live-range budget
  for (int t = 0; t < NT; ++t) {
    const char* lbase = (const char*)Bl + rb + lane * 16;
    int scol = col00 + (t + 2) * BN;   // unconditional (tail reads garbage)

    // ---- phase 0: stage half of t+2, read bv(p0), MFMA -> accA;
    //      exp2 of accB (prev tile's phase 1) interleaves with the MFMAs.
    stage_quarter((char*)Bl + wb, Rb, scol, 0, tid);
    stage_quarter((char*)Bl + wb, Rb, scol, 1, tid);
    {
      i32x8 bv[2][2];
      #pragma unroll
      for (int cf = 0; cf < 2; ++cf)
        #pragma unroll
        for (int h = 0; h < 2; ++h) {
          const int off = (cf * 4 + h * 2) * 1024;
          bv[cf][h] = cat8(*(const i32x4*)(lbase + off),
                           *(const i32x4*)(lbase + off + 1024));
        }
      #pragma unroll
      for (int m = 0; m < 4; ++m) { accA[m][0] = zero; accA[m][1] = zero; }
      #pragma unroll
      for (int m = 0; m < 4; ++m)
        #pragma unroll
        for (int cf = 0; cf < 2; ++cf) {
          accA[m][cf] = mfma_mx(av[m][0], bv[cf][0], accA[m][cf]);
          accA[m][cf] = mfma_mx(av[m][1], bv[cf][1], accA[m][cf]);
        }
      flush_acc(accB, rs);   // independent of accA's MFMAs -> co-issues
    }

    // ---- phase 1: stage other half, read bv(p1), MFMA -> accB;
    //      exp2 of accA interleaves with these MFMAs.
    stage_quarter((char*)Bl + wb, Rb, scol, 2, tid);
    stage_quarter((char*)Bl + wb, Rb, scol, 3, tid);
    {
      i32x8 bv[2][2];
      #pragma unroll
      for (int cf = 0; cf < 2; ++cf)
        #pragma unroll
        for (int h = 0; h < 2; ++h) {
          const int off = (8 + cf * 4 + h * 2) * 1024;
          bv[cf][h] = cat8(*(const i32x4*)(lbase + off),
                           *(const i32x4*)(lbase + off + 1024));
        }
      #pragma unroll
      for (int m = 0; m < 4; ++m) { accB[m][0] = zero; accB[m][1] = zero; }
      #pragma unroll
      for (int m = 0; m < 4; ++m)
        #pragma unroll
        for (int cf = 0; cf < 2; ++cf) {
          accB[m][cf] = mfma_mx(av[m][0], bv[cf][0], accB[m][cf]);
          accB[m][cf] = mfma_mx(av[m][1], bv[cf][1], accB[m][cf]);
        }
      flush_acc(accA, rs);   // independent of accB's MFMAs -> co-issues
    }

    // tile boundary: tile t+1 resident, this tile's 4 loads stay in flight
    asm volatile("s_waitcnt vmcnt(4)" ::: "memory");
    __builtin_amdgcn_s_barrier();

    rb += TS; if (rb == 3 * TS) rb = 0;
    wb += TS; if (wb == 3 * TS) wb = 0;
  }

  asm volatile("s_waitcnt vmcnt(0)" ::: "memory");  // drain tail garbage loads
  flush_acc(accB, rs);   // last tile's phase-1 scores

  // reduce the 16 column-lanes holding the same row, one atomic per row
  #pragma unroll
  for (int k = 0; k < 16; ++k) {
    float v = rs[k];
    v += __shfl_xor(v, 1);
    v += __shfl_xor(v, 2);
    v += __shfl_xor(v, 4);
    v += __shfl_xor(v, 8);
    if (c == 0) {
      int row = row0 + wid * 64 + (k >> 2) * 16 + g * 4 + (k & 3);
      atomicAdd(&row_sum[row], v);
    }
  }

  // ---- fused finalize: last block to finish reduces all rows ----
  __threadfence();                       // make row_sum updates device-visible
  __shared__ int isLast;
  if (tid == 0) isLast = (atomicAdd(done_cnt, 1) == NBLK - 1);
  __syncthreads();
  if (isLast) {
    __threadfence();                     // acquire: invalidate L1 before reads
    float s = 0.f;
    #pragma unroll 4
    for (int i = tid; i < NROWS; i += 256)
      s += __logf(row_sum[i]) - pos[i];
    #pragma unroll
    for (int m = 1; m < 64; m <<= 1) s += __shfl_xor(s, m);
    __shared__ float red[4];
    if (lane == 0) red[wid] = s;
    __syncthreads();
    if (tid == 0)
      out[0] = red[0] + red[1] + red[2] + red[3];  // -loss = sum(lse - pos)
  }
}

extern "C" void kernel_launch(void* const* d_in, const int* in_sizes, int n_in,
                              void* d_out, int out_size, void* d_ws, size_t ws_size,
                              hipStream_t stream) {
  const float* q = (const float*)d_in[0];
  const float* r = (const float*)d_in[1];
  int n = in_sizes[0] / DDIM;  // 8192

  char* w = (char*)d_ws;
  size_t f8Bytes = (size_t)n * DDIM;
  unsigned char* qf8 = (unsigned char*)w;
  unsigned char* rf8 = (unsigned char*)(w + f8Bytes);
  float* pos     = (float*)(w + 2 * f8Bytes);
  float* row_sum = pos + n;
  int*   done    = (int*)(row_sum + n);

  prep_kernel<<<n / 4, 256, 0, stream>>>(q, r, qf8, rf8, pos, row_sum, done);

  dim3 grid(n / BROWS, n / (NT * BN));   // 32 x 16 = 512 blocks
  gemm_lse_kernel<<<grid, 256, 0, stream>>>(qf8, rf8, row_sum, pos,
                                            (float*)d_out, done);
}

// Round 26
// 33.509 us; speedup vs baseline: 1.9681x; 1.9681x over previous
//
#include <hip/hip_runtime.h>
#include <hip/hip_bf16.h>

#define DDIM   256    // K (feature dim)
#define BROWS  256    // block output rows (4 waves x 64 rows)
#define BN      64    // cols per N-tile
#define NT       8    // N-tiles per block -> 512-col chunk
#define TS   (BN * DDIM)   // 16 KB per buffer
#define SQRT_LOG2E 1.2011224087864498f   // sqrt(log2(e)); dot *= log2(e)

typedef float f32x4 __attribute__((ext_vector_type(4)));
typedef int   i32x4 __attribute__((ext_vector_type(4)));
typedef int   i32x8 __attribute__((ext_vector_type(8)));

// v_exp_f32: D = 2^S0 (hardware transcendental)
__device__ __forceinline__ float exp2_hw(float x) {
  return __builtin_amdgcn_exp2f(x);
}

// MX-scaled fp8 MFMA, unit scales (E8M0 127 = 1.0). cbsz=0/blgp=0 -> e4m3.
__device__ __forceinline__ f32x4 mfma_mx(i32x8 a, i32x8 b, f32x4 c) {
  return __builtin_amdgcn_mfma_scale_f32_16x16x128_f8f6f4(
      a, b, c, 0, 0, 0, 0x7F7F7F7F, 0, 0x7F7F7F7F);
}

__device__ __forceinline__ i32x8 cat8(i32x4 lo, i32x4 hi) {
  return __builtin_shufflevector(lo, hi, 0, 1, 2, 3, 4, 5, 6, 7);
}

// pack 4 f32 -> 4 fp8 e4m3 bytes
__device__ __forceinline__ unsigned int pack4_fp8(float a0, float a1, float a2, float a3) {
  int v = __builtin_amdgcn_cvt_pk_fp8_f32(a0, a1, 0, false);   // bytes 0,1
  v = __builtin_amdgcn_cvt_pk_fp8_f32(a2, a3, v, true);        // bytes 2,3
  return (unsigned int)v;
}

// ---- prep: one wave per row; writes sqrt(log2e)-scaled UNIT-NORM fp8 rows
// (so the GEMM dot is s*log2e and the epilogue is a bare exp2) + exact diag.
__global__ __launch_bounds__(256) void prep_kernel(
    const float* __restrict__ q, const float* __restrict__ r,
    unsigned char* __restrict__ qf8, unsigned char* __restrict__ rf8,
    float* __restrict__ pos, float* __restrict__ row_sum,
    float* __restrict__ out) {
  if (blockIdx.x == 0 && threadIdx.x == 0) out[0] = 0.0f;  // finalize atomics
  int lane = threadIdx.x & 63, wave = threadIdx.x >> 6;
  int row = blockIdx.x * 4 + wave;
  size_t base = (size_t)row * DDIM + lane * 4;
  float4 qv = *(const float4*)(q + base);
  float4 rv = *(const float4*)(r + base);
  float qq = qv.x*qv.x + qv.y*qv.y + qv.z*qv.z + qv.w*qv.w;
  float rr = rv.x*rv.x + rv.y*rv.y + rv.z*rv.z + rv.w*rv.w;
  float qr = qv.x*rv.x + qv.y*rv.y + qv.z*rv.z + qv.w*rv.w;
  #pragma unroll
  for (int m = 1; m < 64; m <<= 1) {
    qq += __shfl_xor(qq, m);
    rr += __shfl_xor(rr, m);
    qr += __shfl_xor(qr, m);
  }
  float iq0 = 1.0f / sqrtf(qq);
  float ir0 = 1.0f / sqrtf(rr);
  float iq = iq0 * SQRT_LOG2E;
  float ir = ir0 * SQRT_LOG2E;
  unsigned int qp = pack4_fp8(qv.x*iq, qv.y*iq, qv.z*iq, qv.w*iq);
  unsigned int rp = pack4_fp8(rv.x*ir, rv.y*ir, rv.z*ir, rv.w*ir);
  *(unsigned int*)(qf8 + base) = qp;
  *(unsigned int*)(rf8 + base) = rp;
  if (lane == 0) {
    pos[row] = qr * iq0 * ir0;   // exact f32 diagonal from raw inputs
    row_sum[row] = 0.0f;
  }
}

// stage quarter q of a 64-col fp8 tile: 1 load/thread into the LANE-LINEAR
// layout (R17-validated): chunk (col=p*32+cf*16+c, k16=h*8+g*2+pc) at index
// (p*8+cf*4+h*2+pc)*64 + (g*16+c) -> all ds_reads are base+lane*16+imm,
// zero bank conflicts. SOURCE applies the inverse permutation (rule 21).
__device__ __forceinline__ void stage_quarter(char* dstBase,
                                              const unsigned char* src_base,
                                              int col0, int q, int tid) {
  int ch = q * 256 + tid;              // dest chunk id 0..1023
  int c   = ch & 15;
  int g   = (ch >> 4) & 3;
  int pc  = (ch >> 6) & 1;
  int h   = (ch >> 7) & 1;
  int cf  = (ch >> 8) & 1;
  int p   = (ch >> 9) & 1;
  int col = p * 32 + cf * 16 + c;
  int src = col * 256 + h * 128 + g * 32 + pc * 16;
  __builtin_amdgcn_global_load_lds(
      (const __attribute__((address_space(1))) void*)((const char*)src_base + (size_t)col0 * 256 + src),
      (__attribute__((address_space(3))) void*)(dstBase + ch * 16),
      16, 0, 0);
}

// exp2-accumulate one phase's 32 scores into the per-row partials.
__device__ __forceinline__ void flush_acc(const f32x4 (&acc)[4][2], float (&rs)[16]) {
  #pragma unroll
  for (int m = 0; m < 4; ++m)
    #pragma unroll
    for (int jj = 0; jj < 4; ++jj)
      rs[m * 4 + jj] += exp2_hw(acc[m][0][jj]) + exp2_hw(acc[m][1][jj]);
}

// MX-K128 GEMM+LSE, R17 skeleton + 1-deep acc pipeline: phase p's exp2 ops
// share a basic block with phase p+1's MFMA cluster (separate HW pipes ->
// compiler interleaves; exp2 leaves the critical path). No setprio, no
// branches in the loop body (unconditional staging; tail over-read stays
// inside d_ws and lands in a buffer that is never consumed).
__global__ __launch_bounds__(256, 2) void gemm_lse_kernel(
    const unsigned char* __restrict__ qf8, const unsigned char* __restrict__ rf8,
    float* __restrict__ row_sum) {
  __shared__ __attribute__((aligned(16))) unsigned char Bl[3 * TS];  // 48 KB

  const int tid  = threadIdx.x;
  const int lane = tid & 63;
  const int wid  = tid >> 6;            // 4 waves, each owns 64 rows
  const int g = lane >> 4, c = lane & 15;
  const int row0  = blockIdx.x * BROWS;
  const int col00 = blockIdx.y * (NT * BN);
  const unsigned char* Rb = rf8;

  // A fragments FIRST (oldest in vmcnt order), then stage tiles 0 and 1 —
  // so the pre-loop vmcnt(4) completes av+tile0 and keeps tile1 in flight.
  i32x8 av[4][2];
  const char* Ab = (const char*)qf8;
  #pragma unroll
  for (int m = 0; m < 4; ++m) {
    size_t rb0 = (size_t)(row0 + wid * 64 + m * 16 + c) * 256;
    #pragma unroll
    for (int h = 0; h < 2; ++h) {
      const char* p = Ab + rb0 + h * 128 + g * 32;
      av[m][h] = cat8(*(const i32x4*)(p), *(const i32x4*)(p + 16));
    }
  }
  #pragma unroll
  for (int q = 0; q < 4; ++q) stage_quarter((char*)Bl,      Rb, col00,      q, tid);
  #pragma unroll
  for (int q = 0; q < 4; ++q) stage_quarter((char*)Bl + TS, Rb, col00 + BN, q, tid);

  float rs[16];
  #pragma unroll
  for (int k = 0; k < 16; ++k) rs[k] = 0.0f;

  // tile 0 resident; tile 1's 4 loads stay in flight
  asm volatile("s_waitcnt vmcnt(4)" ::: "memory");
  __builtin_amdgcn_s_barrier();

  const f32x4 zero = {0.f, 0.f, 0.f, 0.f};
  const f32x4 neg  = {-1000.f, -1000.f, -1000.f, -1000.f};  // exp2 -> 0
  f32x4 accA[4][2], accB[4][2];
  #pragma unroll
  for (int m = 0; m < 4; ++m) { accB[m][0] = neg; accB[m][1] = neg; }

  int rb = 0;            // read-buffer byte base (t % 3)
  int wb = 2 * TS;       // write-buffer byte base ((t+2) % 3)
  #pragma unroll 1       // R18 lesson: unrolling blows the live-range budget
  for (int t = 0; t < NT; ++t) {
    const char* lbase = (const char*)Bl + rb + lane * 16;
    int scol = col00 + (t + 2) * BN;   // unconditional (tail reads garbage)

    // ---- phase 0: stage half of t+2, read bv(p0), MFMA -> accA;
    //      exp2 of accB (prev tile's phase 1) interleaves with the MFMAs.
    stage_quarter((char*)Bl + wb, Rb, scol, 0, tid);
    stage_quarter((char*)Bl + wb, Rb, scol, 1, tid);
    {
      i32x8 bv[2][2];
      #pragma unroll
      for (int cf = 0; cf < 2; ++cf)
        #pragma unroll
        for (int h = 0; h < 2; ++h) {
          const int off = (cf * 4 + h * 2) * 1024;
          bv[cf][h] = cat8(*(const i32x4*)(lbase + off),
                           *(const i32x4*)(lbase + off + 1024));
        }
      #pragma unroll
      for (int m = 0; m < 4; ++m) { accA[m][0] = zero; accA[m][1] = zero; }
      #pragma unroll
      for (int m = 0; m < 4; ++m)
        #pragma unroll
        for (int cf = 0; cf < 2; ++cf) {
          accA[m][cf] = mfma_mx(av[m][0], bv[cf][0], accA[m][cf]);
          accA[m][cf] = mfma_mx(av[m][1], bv[cf][1], accA[m][cf]);
        }
      flush_acc(accB, rs);   // independent of accA's MFMAs -> co-issues
    }

    // ---- phase 1: stage other half, read bv(p1), MFMA -> accB;
    //      exp2 of accA interleaves with these MFMAs.
    stage_quarter((char*)Bl + wb, Rb, scol, 2, tid);
    stage_quarter((char*)Bl + wb, Rb, scol, 3, tid);
    {
      i32x8 bv[2][2];
      #pragma unroll
      for (int cf = 0; cf < 2; ++cf)
        #pragma unroll
        for (int h = 0; h < 2; ++h) {
          const int off = (8 + cf * 4 + h * 2) * 1024;
          bv[cf][h] = cat8(*(const i32x4*)(lbase + off),
                           *(const i32x4*)(lbase + off + 1024));
        }
      #pragma unroll
      for (int m = 0; m < 4; ++m) { accB[m][0] = zero; accB[m][1] = zero; }
      #pragma unroll
      for (int m = 0; m < 4; ++m)
        #pragma unroll
        for (int cf = 0; cf < 2; ++cf) {
          accB[m][cf] = mfma_mx(av[m][0], bv[cf][0], accB[m][cf]);
          accB[m][cf] = mfma_mx(av[m][1], bv[cf][1], accB[m][cf]);
        }
      flush_acc(accA, rs);   // independent of accB's MFMAs -> co-issues
    }

    // tile boundary: tile t+1 resident, this tile's 4 loads stay in flight
    asm volatile("s_waitcnt vmcnt(4)" ::: "memory");
    __builtin_amdgcn_s_barrier();

    rb += TS; if (rb == 3 * TS) rb = 0;
    wb += TS; if (wb == 3 * TS) wb = 0;
  }

  asm volatile("s_waitcnt vmcnt(0)" ::: "memory");  // drain tail garbage loads
  flush_acc(accB, rs);   // last tile's phase-1 scores

  // reduce the 16 column-lanes holding the same row, one atomic per row
  #pragma unroll
  for (int k = 0; k < 16; ++k) {
    float v = rs[k];
    v += __shfl_xor(v, 1);
    v += __shfl_xor(v, 2);
    v += __shfl_xor(v, 4);
    v += __shfl_xor(v, 8);
    if (c == 0) {
      int row = row0 + wid * 64 + (k >> 2) * 16 + g * 4 + (k & 3);
      atomicAdd(&row_sum[row], v);
    }
  }
}

// 32 blocks x 256 threads, one row per thread, one atomicAdd per block
// (prep zeroed out[0]).
__global__ __launch_bounds__(256) void finalize_kernel(
    const float* __restrict__ row_sum, const float* __restrict__ pos,
    float* __restrict__ out) {
  int i = blockIdx.x * 256 + threadIdx.x;
  float s = __logf(row_sum[i]) - pos[i];
  #pragma unroll
  for (int m = 1; m < 64; m <<= 1) s += __shfl_xor(s, m);
  __shared__ float red[4];
  if ((threadIdx.x & 63) == 0) red[threadIdx.x >> 6] = s;
  __syncthreads();
  if (threadIdx.x == 0)
    atomicAdd(out, red[0] + red[1] + red[2] + red[3]);  // -loss = sum(lse-pos)
}

extern "C" void kernel_launch(void* const* d_in, const int* in_sizes, int n_in,
                              void* d_out, int out_size, void* d_ws, size_t ws_size,
                              hipStream_t stream) {
  const float* q = (const float*)d_in[0];
  const float* r = (const float*)d_in[1];
  int n = in_sizes[0] / DDIM;  // 8192

  char* w = (char*)d_ws;
  size_t f8Bytes = (size_t)n * DDIM;
  unsigned char* qf8 = (unsigned char*)w;
  unsigned char* rf8 = (unsigned char*)(w + f8Bytes);
  float* pos     = (float*)(w + 2 * f8Bytes);
  float* row_sum = pos + n;

  prep_kernel<<<n / 4, 256, 0, stream>>>(q, r, qf8, rf8, pos, row_sum,
                                         (float*)d_out);

  dim3 grid(n / BROWS, n / (NT * BN));   // 32 x 16 = 512 blocks
  gemm_lse_kernel<<<grid, 256, 0, stream>>>(qf8, rf8, row_sum);

  finalize_kernel<<<n / 256, 256, 0, stream>>>(row_sum, pos, (float*)d_out);
}